// Round 1
// baseline (252.601 us; speedup 1.0000x reference)
//
#include <hip/hip_runtime.h>
#include <hip/hip_bf16.h>

#define SEP_ID 2
#define S_LEN  4096
#define HID    768
#define MAXS   64

using short8  = __attribute__((ext_vector_type(8))) short;  // 8 bf16 (4 VGPRs)
using floatx4 = __attribute__((ext_vector_type(4))) float;  // MFMA accumulator

// ---------------------------------------------------------------------------
// K1: per-row sentence boundaries from sep positions.
// Reference semantics: seg(t)=#seps strictly before t; first sep included in
// sentence 0; later seps excluded; token S-1 excluded iff it's in the trailing
// (post-last-sep) segment and n_sep>0; segments >=64 dumped; empty -> cnt 0.
// ---------------------------------------------------------------------------
__global__ void bounds_kernel(const int* __restrict__ ids,
                              int* __restrict__ sent_start,
                              int* __restrict__ sent_cnt) {
    const int b = blockIdx.x;
    const int t = threadIdx.x;
    const int* row = ids + (size_t)b * S_LEN;

    __shared__ int cnts[256];
    __shared__ int offs[256];
    __shared__ int sep_pos[S_LEN];
    __shared__ int total;

    // each thread scans a contiguous 16-token chunk (preserves ordering)
    int local[16];
    int c = 0;
    const int base = t * 16;
    #pragma unroll
    for (int i = 0; i < 16; ++i) {
        if (row[base + i] == SEP_ID) local[c++] = base + i;
    }
    cnts[t] = c;
    __syncthreads();
    if (t == 0) {
        int s = 0;
        for (int i = 0; i < 256; ++i) { offs[i] = s; s += cnts[i]; }
        total = s;
    }
    __syncthreads();
    {
        int o = offs[t];
        for (int i = 0; i < c; ++i) sep_pos[o + i] = local[i];
    }
    __syncthreads();

    const int n_sep = total;
    if (t < MAXS) {
        const int m = t;
        int start = 0, cnt = 0;
        if (n_sep == 0) {
            if (m == 0) { start = 0; cnt = S_LEN; }      // whole row, no exclusion
        } else if (m < n_sep) {
            if (m == 0) { start = 0; cnt = sep_pos[0] + 1; }   // includes first sep
            else { start = sep_pos[m - 1] + 1; cnt = sep_pos[m] - sep_pos[m - 1] - 1; }
        } else if (m == n_sep) {
            start = sep_pos[n_sep - 1] + 1;              // trailing segment
            cnt = (S_LEN - 1) - start;                   // tokens [start, S-2]
            if (cnt < 0) cnt = 0;
        }
        sent_start[b * MAXS + m] = start;
        sent_cnt[b * MAXS + m]  = cnt;
    }
}

// ---------------------------------------------------------------------------
// K2: per-sentence mean pooling. One block per (b, sentence). 256 threads,
// each owns 3 of the 768 hidden dims. Coalesced dword streams; HBM-bound.
// Output in bf16 for the MFMA GEMMs.
// ---------------------------------------------------------------------------
__global__ __launch_bounds__(256) void pool_kernel(const float* __restrict__ hidden,
                                                   const int* __restrict__ sent_start,
                                                   const int* __restrict__ sent_cnt,
                                                   __hip_bfloat16* __restrict__ sent) {
    const int blk = blockIdx.x;
    const int b = blk >> 6;
    const int t = threadIdx.x;
    const int start = sent_start[blk];
    const int cnt   = sent_cnt[blk];

    float a0 = 0.f, a1 = 0.f, a2 = 0.f;
    const float* base = hidden + ((size_t)b * S_LEN + start) * HID;
    int i = 0;
    for (; i + 1 < cnt; i += 2) {          // 2x unroll -> more loads in flight
        const float* r0 = base + (size_t)i * HID;
        const float* r1 = r0 + HID;
        a0 += r0[t]       + r1[t];
        a1 += r0[t + 256] + r1[t + 256];
        a2 += r0[t + 512] + r1[t + 512];
    }
    if (i < cnt) {
        const float* r0 = base + (size_t)i * HID;
        a0 += r0[t]; a1 += r0[t + 256]; a2 += r0[t + 512];
    }
    const float inv = (cnt > 0) ? 1.0f / (float)cnt : 0.0f;   // empty -> zeros
    __hip_bfloat16* o = sent + (size_t)blk * HID;
    o[t]       = __float2bfloat16(a0 * inv);
    o[t + 256] = __float2bfloat16(a1 * inv);
    o[t + 512] = __float2bfloat16(a2 * inv);
}

// ---------------------------------------------------------------------------
// K3: transpose + fp32->bf16 convert: in[K][N] -> out[N][K].
// Gives the GEMM a B^T layout so LDS staging and B-fragment reads are
// contiguous 16B, same as A.
// ---------------------------------------------------------------------------
__global__ __launch_bounds__(256) void tconv_kernel(const float* __restrict__ in,
                                                    __hip_bfloat16* __restrict__ out,
                                                    int K, int N) {
    __shared__ float tile[32][33];
    const int n0 = blockIdx.x * 32;
    const int k0 = blockIdx.y * 32;
    const int c = threadIdx.x & 31;
    const int r = threadIdx.x >> 5;   // 8 rows per pass
    #pragma unroll
    for (int i = 0; i < 32; i += 8)
        tile[r + i][c] = in[(size_t)(k0 + r + i) * N + n0 + c];
    __syncthreads();
    #pragma unroll
    for (int i = 0; i < 32; i += 8)
        out[(size_t)(n0 + r + i) * K + k0 + c] = __float2bfloat16(tile[c][r + i]);
}

__device__ __forceinline__ float gelu_exact(float x) {
    return 0.5f * x * (1.0f + erff(x * 0.70710678118654752f));
}

// ---------------------------------------------------------------------------
// K4/K5: bf16 MFMA GEMM: out = act(A[M,K] * BT[N,K]^T + bias), act = exact GELU.
// Block tile 64x64, BK=32, 4 waves each computing a 32x32 quadrant as 2x2
// mfma_f32_16x16x32_bf16 tiles. LDS leading stride 40 bf16 (80B) to spread
// banks for the b128 fragment reads.
// A-frag: row=lane&15, k=(lane>>4)*8+j ; B-frag: col=lane&15, same k.
// C/D:    col=lane&15, row=(lane>>4)*4+reg.
// ---------------------------------------------------------------------------
__global__ __launch_bounds__(256) void gemm_kernel(const __hip_bfloat16* __restrict__ A,
                                                   const __hip_bfloat16* __restrict__ BT,
                                                   const float* __restrict__ bias,
                                                   void* __restrict__ out,
                                                   int M, int N, int K, int out_bf16) {
    const int n0 = blockIdx.x * 64;
    const int m0 = blockIdx.y * 64;
    const int t = threadIdx.x;
    const int w = t >> 6, l = t & 63;
    const int wm = (w >> 1) * 32;     // wave's row offset in block tile
    const int wn = (w & 1) * 32;      // wave's col offset

    __shared__ __hip_bfloat16 Al[64][40];
    __shared__ __hip_bfloat16 Bl[64][40];

    floatx4 acc[2][2] = {};

    // staging assignment: thread t loads 8 bf16 of row r, k-chunk ch
    const int r  = t >> 2;
    const int ch = (t & 3) * 8;
    const __hip_bfloat16* Ag = A  + (size_t)(m0 + r) * K + ch;
    const __hip_bfloat16* Bg = BT + (size_t)(n0 + r) * K + ch;

    const int lr = l & 15;
    const int kq = (l >> 4) * 8;

    for (int k0 = 0; k0 < K; k0 += 32) {
        short8 av = *(const short8*)(Ag + k0);
        short8 bv = *(const short8*)(Bg + k0);
        __syncthreads();                       // prior iter's frag reads done
        *(short8*)(&Al[r][ch]) = av;
        *(short8*)(&Bl[r][ch]) = bv;
        __syncthreads();

        short8 a0 = *(const short8*)(&Al[wm + lr][kq]);
        short8 a1 = *(const short8*)(&Al[wm + 16 + lr][kq]);
        short8 b0 = *(const short8*)(&Bl[wn + lr][kq]);
        short8 b1 = *(const short8*)(&Bl[wn + 16 + lr][kq]);

        acc[0][0] = __builtin_amdgcn_mfma_f32_16x16x32_bf16(a0, b0, acc[0][0], 0, 0, 0);
        acc[0][1] = __builtin_amdgcn_mfma_f32_16x16x32_bf16(a0, b1, acc[0][1], 0, 0, 0);
        acc[1][0] = __builtin_amdgcn_mfma_f32_16x16x32_bf16(a1, b0, acc[1][0], 0, 0, 0);
        acc[1][1] = __builtin_amdgcn_mfma_f32_16x16x32_bf16(a1, b1, acc[1][1], 0, 0, 0);
    }

    // epilogue: bias + exact GELU, write bf16 or f32
    #pragma unroll
    for (int i = 0; i < 2; ++i) {
        #pragma unroll
        for (int j = 0; j < 2; ++j) {
            const int col  = n0 + wn + j * 16 + (l & 15);
            const int rowb = m0 + wm + i * 16 + (l >> 4) * 4;
            const float bv = bias[col];
            #pragma unroll
            for (int rg = 0; rg < 4; ++rg) {
                float x = acc[i][j][rg] + bv;
                float g = gelu_exact(x);
                if (out_bf16)
                    ((__hip_bfloat16*)out)[(size_t)(rowb + rg) * N + col] = __float2bfloat16(g);
                else
                    ((float*)out)[(size_t)(rowb + rg) * N + col] = g;
            }
        }
    }
}

// ---------------------------------------------------------------------------
// K6: logits = x2[512,256] @ W3[256,2] + b3, fp32. One wave per row.
// ---------------------------------------------------------------------------
__global__ __launch_bounds__(256) void head_kernel(const float* __restrict__ x2,
                                                   const float* __restrict__ W3,
                                                   const float* __restrict__ b3,
                                                   float* __restrict__ out) {
    const int w = threadIdx.x >> 6, l = threadIdx.x & 63;
    const int row = blockIdx.x * 4 + w;          // 512 rows
    const float* xr = x2 + (size_t)row * 256;
    float s0 = 0.f, s1 = 0.f;
    #pragma unroll
    for (int j = 0; j < 4; ++j) {
        const float v = xr[l + 64 * j];
        s0 += v * W3[(l + 64 * j) * 2 + 0];
        s1 += v * W3[(l + 64 * j) * 2 + 1];
    }
    #pragma unroll
    for (int off = 32; off; off >>= 1) {
        s0 += __shfl_down(s0, off);
        s1 += __shfl_down(s1, off);
    }
    if (l == 0) {
        out[row * 2 + 0] = s0 + b3[0];
        out[row * 2 + 1] = s1 + b3[1];
    }
}

// ---------------------------------------------------------------------------
extern "C" void kernel_launch(void* const* d_in, const int* in_sizes, int n_in,
                              void* d_out, int out_size, void* d_ws, size_t ws_size,
                              hipStream_t stream) {
    const float* hidden = (const float*)d_in[0];
    const int*   ids    = (const int*)d_in[1];
    const float* W1     = (const float*)d_in[2];
    const float* b1     = (const float*)d_in[3];
    const float* W2     = (const float*)d_in[4];
    const float* b2     = (const float*)d_in[5];
    const float* W3     = (const float*)d_in[6];
    const float* b3     = (const float*)d_in[7];
    float* out = (float*)d_out;

    char* ws = (char*)d_ws;
    int* sent_start        = (int*)(ws + 0);                      // 2 KB
    int* sent_cnt          = (int*)(ws + 2048);                   // 2 KB
    __hip_bfloat16* sentb  = (__hip_bfloat16*)(ws + 4096);        // 512x768 bf16
    __hip_bfloat16* W1T    = (__hip_bfloat16*)(ws + 790528);      // 4096x768 bf16
    __hip_bfloat16* W2T    = (__hip_bfloat16*)(ws + 7081984);     // 256x4096 bf16
    __hip_bfloat16* x1     = (__hip_bfloat16*)(ws + 9179136);     // 512x4096 bf16
    float* x2              = (float*)(ws + 13373440);             // 512x256 f32
    // total ws use: ~13.9 MB

    bounds_kernel<<<8, 256, 0, stream>>>(ids, sent_start, sent_cnt);
    pool_kernel<<<512, 256, 0, stream>>>(hidden, sent_start, sent_cnt, sentb);
    tconv_kernel<<<dim3(4096 / 32, 768 / 32), 256, 0, stream>>>(W1, W1T, 768, 4096);
    tconv_kernel<<<dim3(256 / 32, 4096 / 32), 256, 0, stream>>>(W2, W2T, 4096, 256);
    gemm_kernel<<<dim3(4096 / 64, 512 / 64), 256, 0, stream>>>(sentb, W1T, b1, x1,
                                                               512, 4096, 768, 1);
    gemm_kernel<<<dim3(256 / 64, 512 / 64), 256, 0, stream>>>(x1, W2T, b2, x2,
                                                              512, 256, 4096, 0);
    head_kernel<<<128, 256, 0, stream>>>(x2, W3, b3, out);
}

// Round 2
// 207.754 us; speedup vs baseline: 1.2159x; 1.2159x over previous
//
#include <hip/hip_runtime.h>
#include <hip/hip_bf16.h>

#define SEP_ID 2
#define S_LEN  4096
#define HID    768
#define MAXS   64

using short8  = __attribute__((ext_vector_type(8))) short;  // 8 bf16 (4 VGPRs)
using floatx4 = __attribute__((ext_vector_type(4))) float;  // MFMA accumulator

// ---------------------------------------------------------------------------
// K1: per-row sentence boundaries from sep positions. (unchanged, correct)
// ---------------------------------------------------------------------------
__global__ void bounds_kernel(const int* __restrict__ ids,
                              int* __restrict__ sent_start,
                              int* __restrict__ sent_cnt) {
    const int b = blockIdx.x;
    const int t = threadIdx.x;
    const int* row = ids + (size_t)b * S_LEN;

    __shared__ int cnts[256];
    __shared__ int offs[256];
    __shared__ int sep_pos[S_LEN];
    __shared__ int total;

    int local[16];
    int c = 0;
    const int base = t * 16;
    #pragma unroll
    for (int i = 0; i < 16; ++i) {
        if (row[base + i] == SEP_ID) local[c++] = base + i;
    }
    cnts[t] = c;
    __syncthreads();
    if (t == 0) {
        int s = 0;
        for (int i = 0; i < 256; ++i) { offs[i] = s; s += cnts[i]; }
        total = s;
    }
    __syncthreads();
    {
        int o = offs[t];
        for (int i = 0; i < c; ++i) sep_pos[o + i] = local[i];
    }
    __syncthreads();

    const int n_sep = total;
    if (t < MAXS) {
        const int m = t;
        int start = 0, cnt = 0;
        if (n_sep == 0) {
            if (m == 0) { start = 0; cnt = S_LEN; }
        } else if (m < n_sep) {
            if (m == 0) { start = 0; cnt = sep_pos[0] + 1; }
            else { start = sep_pos[m - 1] + 1; cnt = sep_pos[m] - sep_pos[m - 1] - 1; }
        } else if (m == n_sep) {
            start = sep_pos[n_sep - 1] + 1;
            cnt = (S_LEN - 1) - start;
            if (cnt < 0) cnt = 0;
        }
        sent_start[b * MAXS + m] = start;
        sent_cnt[b * MAXS + m]  = cnt;
    }
}

// ---------------------------------------------------------------------------
// K2: per-sentence mean pooling, float4 + 4-row unroll for MLP (memory-level
// parallelism): 4x 16B loads in flight per thread; 192 thr/block (768/4).
// ---------------------------------------------------------------------------
__global__ __launch_bounds__(192) void pool_kernel(const float* __restrict__ hidden,
                                                   const int* __restrict__ sent_start,
                                                   const int* __restrict__ sent_cnt,
                                                   __hip_bfloat16* __restrict__ sent) {
    const int blk = blockIdx.x;
    const int b = blk >> 6;
    const int t = threadIdx.x;          // 0..191, one float4 column each
    const int start = sent_start[blk];
    const int cnt   = sent_cnt[blk];

    const float4* base = (const float4*)(hidden + ((size_t)b * S_LEN + start) * HID);
    float ax = 0.f, ay = 0.f, az = 0.f, aw = 0.f;
    int i = 0;
    for (; i + 4 <= cnt; i += 4) {
        float4 v0 = base[(size_t)(i + 0) * 192 + t];
        float4 v1 = base[(size_t)(i + 1) * 192 + t];
        float4 v2 = base[(size_t)(i + 2) * 192 + t];
        float4 v3 = base[(size_t)(i + 3) * 192 + t];
        ax += v0.x + v1.x + v2.x + v3.x;
        ay += v0.y + v1.y + v2.y + v3.y;
        az += v0.z + v1.z + v2.z + v3.z;
        aw += v0.w + v1.w + v2.w + v3.w;
    }
    for (; i < cnt; ++i) {
        float4 v = base[(size_t)i * 192 + t];
        ax += v.x; ay += v.y; az += v.z; aw += v.w;
    }
    const float inv = (cnt > 0) ? 1.0f / (float)cnt : 0.0f;
    __hip_bfloat16* o = sent + (size_t)blk * HID + t * 4;
    o[0] = __float2bfloat16(ax * inv);
    o[1] = __float2bfloat16(ay * inv);
    o[2] = __float2bfloat16(az * inv);
    o[3] = __float2bfloat16(aw * inv);
}

// ---------------------------------------------------------------------------
// K3: both weight transposes (fp32 [K][N] -> bf16 [N][K]) in ONE launch.
// W1: 768x4096 -> blocks [0,3072); W2: 4096x256 -> blocks [3072,4096).
// ---------------------------------------------------------------------------
__global__ __launch_bounds__(256) void tconv_kernel(const float* __restrict__ W1,
                                                    const float* __restrict__ W2,
                                                    __hip_bfloat16* __restrict__ W1T,
                                                    __hip_bfloat16* __restrict__ W2T) {
    __shared__ float tile[32][33];
    int id = blockIdx.x;
    const float* in; __hip_bfloat16* out; int K, N, n0, k0;
    if (id < 3072) {            // W1: N=4096 (128 n-blocks), K=768 (24 k-blocks)
        in = W1; out = W1T; K = 768; N = 4096;
        n0 = (id & 127) * 32; k0 = (id >> 7) * 32;
    } else {                    // W2: N=256 (8 n-blocks), K=4096 (128 k-blocks)
        id -= 3072;
        in = W2; out = W2T; K = 4096; N = 256;
        n0 = (id & 7) * 32; k0 = (id >> 3) * 32;
    }
    const int c = threadIdx.x & 31;
    const int r = threadIdx.x >> 5;
    #pragma unroll
    for (int i = 0; i < 32; i += 8)
        tile[r + i][c] = in[(size_t)(k0 + r + i) * N + n0 + c];
    __syncthreads();
    #pragma unroll
    for (int i = 0; i < 32; i += 8)
        out[(size_t)(n0 + r + i) * K + k0 + c] = __float2bfloat16(tile[c][r + i]);
}

__device__ __forceinline__ float gelu_exact(float x) {
    return 0.5f * x * (1.0f + erff(x * 0.70710678118654752f));
}

// ---------------------------------------------------------------------------
// K4: GEMM1  x1 = GELU(sent[512,768] @ W1T[4096,768]^T + b1), bf16 out.
// Block tile 64(M)x128(N), BK=32; 4 waves in 2x2, each wave 32x64 via
// 2x4 of mfma_f32_16x16x32_bf16 -> 8 MFMA per wave-iter.
// LDS stride 40 bf16 (80B) spreads banks for the b128 fragment reads.
// ---------------------------------------------------------------------------
__global__ __launch_bounds__(256) void gemm1_kernel(const __hip_bfloat16* __restrict__ A,
                                                    const __hip_bfloat16* __restrict__ BT,
                                                    const float* __restrict__ bias,
                                                    __hip_bfloat16* __restrict__ out) {
    const int n0 = blockIdx.x * 128;   // 32
    const int m0 = blockIdx.y * 64;    // 8
    const int t = threadIdx.x;
    const int w = t >> 6, l = t & 63;
    const int wm = (w >> 1) * 32;
    const int wn = (w & 1) * 64;

    __shared__ __hip_bfloat16 Al[64][40];
    __shared__ __hip_bfloat16 Bl[128][40];

    floatx4 acc[2][4] = {};

    const int r  = t >> 2;            // 0..63
    const int ch = (t & 3) * 8;       // 0,8,16,24
    const __hip_bfloat16* Ag  = A  + (size_t)(m0 + r) * 768 + ch;
    const __hip_bfloat16* Bg0 = BT + (size_t)(n0 + r) * 768 + ch;
    const __hip_bfloat16* Bg1 = BT + (size_t)(n0 + 64 + r) * 768 + ch;

    const int lr = l & 15;
    const int kq = (l >> 4) * 8;

    for (int k0 = 0; k0 < 768; k0 += 32) {
        short8 av  = *(const short8*)(Ag  + k0);
        short8 bv0 = *(const short8*)(Bg0 + k0);
        short8 bv1 = *(const short8*)(Bg1 + k0);
        __syncthreads();
        *(short8*)(&Al[r][ch])      = av;
        *(short8*)(&Bl[r][ch])      = bv0;
        *(short8*)(&Bl[64 + r][ch]) = bv1;
        __syncthreads();

        short8 a0 = *(const short8*)(&Al[wm + lr][kq]);
        short8 a1 = *(const short8*)(&Al[wm + 16 + lr][kq]);
        #pragma unroll
        for (int j = 0; j < 4; ++j) {
            short8 bj = *(const short8*)(&Bl[wn + j * 16 + lr][kq]);
            acc[0][j] = __builtin_amdgcn_mfma_f32_16x16x32_bf16(a0, bj, acc[0][j], 0, 0, 0);
            acc[1][j] = __builtin_amdgcn_mfma_f32_16x16x32_bf16(a1, bj, acc[1][j], 0, 0, 0);
        }
    }

    #pragma unroll
    for (int i = 0; i < 2; ++i) {
        #pragma unroll
        for (int j = 0; j < 4; ++j) {
            const int col  = n0 + wn + j * 16 + lr;
            const int rowb = m0 + wm + i * 16 + (l >> 4) * 4;
            const float bv = bias[col];
            #pragma unroll
            for (int rg = 0; rg < 4; ++rg) {
                float x = acc[i][j][rg] + bv;
                out[(size_t)(rowb + rg) * 4096 + col] = __float2bfloat16(gelu_exact(x));
            }
        }
    }
}

// ---------------------------------------------------------------------------
// K5: GEMM2 partials: part[s] = x1[512,4096-slice] @ W2T[256,4096-slice]^T.
// Split-K=8 (512 K per split) for parallelism: grid 4x8x8 = 256 blocks.
// 64x64 tile, 4 waves 2x2, each 32x32 via 2x2 MFMA. fp32 partial out.
// ---------------------------------------------------------------------------
__global__ __launch_bounds__(256) void gemm2_kernel(const __hip_bfloat16* __restrict__ A,
                                                    const __hip_bfloat16* __restrict__ BT,
                                                    float* __restrict__ part) {
    const int n0 = blockIdx.x * 64;     // 4
    const int m0 = blockIdx.y * 64;     // 8
    const int s  = blockIdx.z;          // 8
    const int kb = s * 512;
    const int t = threadIdx.x;
    const int w = t >> 6, l = t & 63;
    const int wm = (w >> 1) * 32;
    const int wn = (w & 1) * 32;

    __shared__ __hip_bfloat16 Al[64][40];
    __shared__ __hip_bfloat16 Bl[64][40];

    floatx4 acc[2][2] = {};

    const int r  = t >> 2;
    const int ch = (t & 3) * 8;
    const __hip_bfloat16* Ag = A  + (size_t)(m0 + r) * 4096 + kb + ch;
    const __hip_bfloat16* Bg = BT + (size_t)(n0 + r) * 4096 + kb + ch;

    const int lr = l & 15;
    const int kq = (l >> 4) * 8;

    for (int k0 = 0; k0 < 512; k0 += 32) {
        short8 av = *(const short8*)(Ag + k0);
        short8 bv = *(const short8*)(Bg + k0);
        __syncthreads();
        *(short8*)(&Al[r][ch]) = av;
        *(short8*)(&Bl[r][ch]) = bv;
        __syncthreads();

        short8 a0 = *(const short8*)(&Al[wm + lr][kq]);
        short8 a1 = *(const short8*)(&Al[wm + 16 + lr][kq]);
        short8 b0 = *(const short8*)(&Bl[wn + lr][kq]);
        short8 b1 = *(const short8*)(&Bl[wn + 16 + lr][kq]);

        acc[0][0] = __builtin_amdgcn_mfma_f32_16x16x32_bf16(a0, b0, acc[0][0], 0, 0, 0);
        acc[0][1] = __builtin_amdgcn_mfma_f32_16x16x32_bf16(a0, b1, acc[0][1], 0, 0, 0);
        acc[1][0] = __builtin_amdgcn_mfma_f32_16x16x32_bf16(a1, b0, acc[1][0], 0, 0, 0);
        acc[1][1] = __builtin_amdgcn_mfma_f32_16x16x32_bf16(a1, b1, acc[1][1], 0, 0, 0);
    }

    float* po = part + (size_t)s * 512 * 256;
    #pragma unroll
    for (int i = 0; i < 2; ++i) {
        #pragma unroll
        for (int j = 0; j < 2; ++j) {
            const int col  = n0 + wn + j * 16 + lr;
            const int rowb = m0 + wm + i * 16 + (l >> 4) * 4;
            #pragma unroll
            for (int rg = 0; rg < 4; ++rg)
                po[(size_t)(rowb + rg) * 256 + col] = acc[i][j][rg];
        }
    }
}

// ---------------------------------------------------------------------------
// K6: fused reduce(split-K partials) + b2 + GELU + head GEMM (W3[256,2]+b3).
// One block per output row; thread c owns column c of x2.
// ---------------------------------------------------------------------------
__global__ __launch_bounds__(256) void rh_kernel(const float* __restrict__ part,
                                                 const float* __restrict__ b2,
                                                 const float* __restrict__ W3,
                                                 const float* __restrict__ b3,
                                                 float* __restrict__ out) {
    const int row = blockIdx.x;     // 512
    const int c = threadIdx.x;      // 256
    const int w = c >> 6, l = c & 63;

    float s = 0.f;
    #pragma unroll
    for (int k = 0; k < 8; ++k)
        s += part[((size_t)k * 512 + row) * 256 + c];
    const float x = gelu_exact(s + b2[c]);
    float y0 = x * W3[c * 2 + 0];
    float y1 = x * W3[c * 2 + 1];
    #pragma unroll
    for (int off = 32; off; off >>= 1) {
        y0 += __shfl_down(y0, off);
        y1 += __shfl_down(y1, off);
    }
    __shared__ float r0[4], r1[4];
    if (l == 0) { r0[w] = y0; r1[w] = y1; }
    __syncthreads();
    if (c == 0) out[row * 2 + 0] = r0[0] + r0[1] + r0[2] + r0[3] + b3[0];
    if (c == 1) out[row * 2 + 1] = r1[0] + r1[1] + r1[2] + r1[3] + b3[1];
}

// ---------------------------------------------------------------------------
extern "C" void kernel_launch(void* const* d_in, const int* in_sizes, int n_in,
                              void* d_out, int out_size, void* d_ws, size_t ws_size,
                              hipStream_t stream) {
    const float* hidden = (const float*)d_in[0];
    const int*   ids    = (const int*)d_in[1];
    const float* W1     = (const float*)d_in[2];
    const float* b1     = (const float*)d_in[3];
    const float* W2     = (const float*)d_in[4];
    const float* b2     = (const float*)d_in[5];
    const float* W3     = (const float*)d_in[6];
    const float* b3     = (const float*)d_in[7];
    float* out = (float*)d_out;

    char* ws = (char*)d_ws;
    int* sent_start        = (int*)(ws + 0);                      // 2 KB
    int* sent_cnt          = (int*)(ws + 2048);                   // 2 KB
    __hip_bfloat16* sentb  = (__hip_bfloat16*)(ws + 4096);        // 512x768 bf16
    __hip_bfloat16* W1T    = (__hip_bfloat16*)(ws + 790528);      // 4096x768 bf16
    __hip_bfloat16* W2T    = (__hip_bfloat16*)(ws + 7081984);     // 256x4096 bf16
    __hip_bfloat16* x1     = (__hip_bfloat16*)(ws + 9179136);     // 512x4096 bf16
    float* part            = (float*)(ws + 13373440);             // 8x512x256 f32
    // total ws use: ~17.6 MB

    bounds_kernel<<<8, 256, 0, stream>>>(ids, sent_start, sent_cnt);
    pool_kernel<<<512, 192, 0, stream>>>(hidden, sent_start, sent_cnt, sentb);
    tconv_kernel<<<4096, 256, 0, stream>>>(W1, W2, W1T, W2T);
    gemm1_kernel<<<dim3(32, 8), 256, 0, stream>>>(sentb, W1T, b1, x1);
    gemm2_kernel<<<dim3(4, 8, 8), 256, 0, stream>>>(x1, W2T, part);
    rh_kernel<<<512, 256, 0, stream>>>(part, b2, W3, b3, out);
}